// Round 8
// baseline (284.780 us; speedup 1.0000x reference)
//
#include <hip/hip_runtime.h>
#include <hip/hip_bf16.h>
#include <stdint.h>

#define NTOK 8192
#define XSTRIDE 259
#define LOG2E 1.4426950408889634f
#define DECC (-3.4712336270551023f)   /* -4 + log2(log2 e) */
#define KSPLIT 8
#define SPLEN (NTOK / KSPLIT)   /* 1024 */
#define BN 64
#define ITERS (SPLEN / BN)      /* 16 */

typedef __bf16 bf16x8 __attribute__((ext_vector_type(8)));
typedef float f32x4 __attribute__((ext_vector_type(4)));
typedef float f32x16 __attribute__((ext_vector_type(16)));
typedef unsigned short u16;

union BF8 { u16 u[8]; bf16x8 v; };
union PW  { uint32_t u[4]; bf16x8 v; };

__device__ __forceinline__ u16 f2bf(float f) {
  uint32_t u = __float_as_uint(f);
  u += 0x7FFFu + ((u >> 16) & 1u);
  return (u16)(u >> 16);
}
__device__ __forceinline__ float bf2f(u16 h) {
  return __uint_as_float(((uint32_t)h) << 16);
}
__device__ __forceinline__ float exp2_hw(float x) {
  float r; asm("v_exp_f32 %0, %1" : "=v"(r) : "v"(x)); return r;
}
__device__ __forceinline__ f32x4 mfma16(bf16x8 a, bf16x8 b, f32x4 c) {
  return __builtin_amdgcn_mfma_f32_16x16x32_bf16(a, b, c, 0, 0, 0);
}
__device__ __forceinline__ f32x16 mfma32(bf16x8 a, bf16x8 b, f32x16 c) {
  return __builtin_amdgcn_mfma_f32_32x32x16_bf16(a, b, c, 0, 0, 0);
}
__device__ __forceinline__ void async16(const void* g, void* l) {
  __builtin_amdgcn_global_load_lds(
      (const __attribute__((address_space(1))) uint32_t*)g,
      (__attribute__((address_space(3))) uint32_t*)l, 16, 0, 0);
}
__device__ __forceinline__ void bsplit(float v, u16& h, u16& l) {
  h = f2bf(v);
  l = f2bf(v - bf2f(h));
}

// ---------------------------------------------------------------------------
// Kernel 0 (tiny prep, 56 blocks): blocks 0..23 = W^T transpose via LDS;
//  blocks 24..55 = position vectors (1 row/thread); block 24 zeroes cnt.
//  Xb intermediate DELETED (qkv reads X directly) — prep is now ~3us.
// ---------------------------------------------------------------------------
__global__ __launch_bounds__(256) void prep_kernel(
    const float* __restrict__ X, const float* __restrict__ WQ,
    const float* __restrict__ WK, const float* __restrict__ WV,
    u16* __restrict__ Qp, u16* __restrict__ Kp, u16* __restrict__ Wt,
    int* __restrict__ cnt) {
  const int bid = blockIdx.x;
  const int t = threadIdx.x;
  if (bid < 24) {
    // ---- W transpose: Wt[o_global][k] = bf16(W[k][o]), coalesced ----
    __shared__ u16 T[32 * 264];       // 32 o x 256 k (+8 pad)
    const int which = bid >> 3, ob = bid & 7;
    const float* W = (which == 0) ? WQ : ((which == 1) ? WK : WV);
    const int kk = t >> 5, oo = t & 31;
#pragma unroll
    for (int kc = 0; kc < 32; ++kc) {
      const int k = kc * 8 + kk;
      T[oo * 264 + k] = f2bf(W[(size_t)k * 256 + ob * 32 + oo]);
    }
    __syncthreads();
#pragma unroll
    for (int i = 0; i < 4; ++i) {
      int chn = i * 256 + t;          // 1024 chunks of 16B
      int o2 = chn >> 5, s = chn & 31;
      uint4 d = *(const uint4*)(T + o2 * 264 + s * 8);
      *(uint4*)(Wt + (size_t)(which * 256 + ob * 32 + o2) * 256 + s * 8) = d;
    }
  } else {
    if (bid == 24 && t < 32) cnt[t] = 0;
    const int r = (bid - 24) * 256 + t;
    const float* pp = X + (size_t)r * XSTRIDE + 256;
    const float x = pp[0], y = pp[1], z = pp[2];
    const float w = 0.5f * (x * x + y * y + z * z);
    u16 xh, xl, yh, yl, zh, zl, wh, wl;
    bsplit(x, xh, xl); bsplit(y, yh, yl); bsplit(z, zh, zl); bsplit(w, wh, wl);
    const u16 one = 0x3F80u;
    const u16 SGN = 0x8000u;
    union { u16 u[16]; uint4 v4[2]; } uq, uk;
    uq.u[0] = wh;  uk.u[0] = one;
    uq.u[1] = wl;  uk.u[1] = one;
    uq.u[2] = one; uk.u[2] = wh;
    uq.u[3] = one; uk.u[3] = wl;
    uq.u[4] = (u16)(xh ^ SGN); uk.u[4] = xh;
    uq.u[5] = (u16)(xh ^ SGN); uk.u[5] = xl;
    uq.u[6] = (u16)(xl ^ SGN); uk.u[6] = xh;
    uq.u[7] = (u16)(yh ^ SGN); uk.u[7] = yh;
    uq.u[8] = (u16)(yh ^ SGN); uk.u[8] = yl;
    uq.u[9] = (u16)(yl ^ SGN); uk.u[9] = yh;
    uq.u[10] = (u16)(zh ^ SGN); uk.u[10] = zh;
    uq.u[11] = (u16)(zh ^ SGN); uk.u[11] = zl;
    uq.u[12] = (u16)(zl ^ SGN); uk.u[12] = zh;
    uq.u[13] = 0; uk.u[13] = 0;
    uq.u[14] = 0; uk.u[14] = 0;
    uq.u[15] = 0; uk.u[15] = 0;
    ((uint4*)Qp)[r * 2] = uq.v4[0];
    ((uint4*)Qp)[r * 2 + 1] = uq.v4[1];
    ((uint4*)Kp)[r * 2] = uk.v4[0];
    ((uint4*)Kp)[r * 2 + 1] = uk.v4[1];
  }
}

// ---------------------------------------------------------------------------
// Kernel 1: QKV projection (128 rowblocks x 3 matrices), R7 structure with
//  X read DIRECTLY (f32 + inline f2bf) — Xb intermediate and its launch
//  dependency removed. W dbuf staging + LDS-bounced coalesced stores kept.
// ---------------------------------------------------------------------------
__global__ __launch_bounds__(256) void qkv_kernel(
    const float* __restrict__ X, const u16* __restrict__ Wt,
    const float* __restrict__ bQ, const float* __restrict__ bK,
    const float* __restrict__ bV,
    u16* __restrict__ Qb, u16* __restrict__ Kb, u16* __restrict__ Vt) {
  __shared__ u16 wt[2][64 * 256];   // 32KB x2: W dbuf; dead buf = C bounce
  const int tid = threadIdx.x;
  const int lane = tid & 63;
  const int wave = tid >> 6;
  const int l15 = lane & 15;
  const int q4 = lane >> 4;
  const int rb = blockIdx.x;         // 0..127 (64-row blocks)
  const int which = blockIdx.y;      // 0..2
  const float* bias = (which == 0) ? bQ : ((which == 1) ? bK : bV);
  const int grow0 = rb * 64;

  // xa: this block's 64 rows read from X f32 once (inline bf16 convert)
  bf16x8 xa[8];
  {
    const int row = grow0 + wave * 16 + l15;
    const float* xp = X + (size_t)row * XSTRIDE;
#pragma unroll
    for (int kc = 0; kc < 8; ++kc) {
      BF8 u;
#pragma unroll
      for (int j = 0; j < 8; ++j) u.u[j] = f2bf(xp[kc * 32 + q4 * 8 + j]);
      xa[kc] = u.v;
    }
  }

#define STAGEW(C_, B_)                                                        \
  do {                                                                        \
    const u16* Wsrc = Wt + (size_t)(which * 256 + (C_) * 64) * 256;           \
    const int rb0 = wave * 16;                                                \
    _Pragma("unroll")                                                         \
    for (int i = 0; i < 8; ++i) {                                             \
      int r = rb0 + i * 2 + (lane >> 5);                                      \
      int cc = (lane & 31) ^ (r & 7);                                         \
      async16(Wsrc + (size_t)r * 256 + cc * 8, &wt[B_][(rb0 + i * 2) * 256]); \
    }                                                                         \
  } while (0)

  STAGEW(0, 0);

#pragma unroll 1
  for (int c = 0; c < 4; ++c) {
    const int cur = c & 1;
    const int c0 = c * 64;
    asm volatile("s_waitcnt vmcnt(0)" ::: "memory");
    __syncthreads();
    if (c < 3) STAGEW(c + 1, cur ^ 1);

    f32x4 acc[4];
#pragma unroll
    for (int nt = 0; nt < 4; ++nt) acc[nt] = (f32x4){0.f, 0.f, 0.f, 0.f};
#pragma unroll
    for (int kc = 0; kc < 8; ++kc) {
#pragma unroll
      for (int nt = 0; nt < 4; ++nt) {
        bf16x8 wf = *(const bf16x8*)(&wt[cur][(nt * 16 + l15) * 256 +
                                     (((kc * 4 + q4) ^ (l15 & 7)) * 8)]);
        acc[nt] = mfma16(xa[kc], wf, acc[nt]);
      }
    }
    float bc[4];
#pragma unroll
    for (int nt = 0; nt < 4; ++nt) bc[nt] = bias[c0 + nt * 16 + l15];

    __syncthreads();          // all waves done reading wt[cur]
    u16* smem = &wt[cur][0];  // dead W buffer -> C-tile bounce

    if (which == 2) {
      // transposed tile Tv[col 64][row 64 + pad8]
#pragma unroll
      for (int nt = 0; nt < 4; ++nt) {
        const int lcol = nt * 16 + l15;
        union { u16 u[4]; uint2 w; } p;
#pragma unroll
        for (int r = 0; r < 4; ++r) p.u[r] = f2bf(acc[nt][r] + bc[nt]);
        *(uint2*)(smem + lcol * 72 + wave * 16 + q4 * 4) = p.w;
      }
      __syncthreads();
#pragma unroll
      for (int i = 0; i < 2; ++i) {
        int chn = i * 256 + tid;        // 512 chunks of 16B
        int lcol = chn >> 3, s = chn & 7;
        uint4 d = *(const uint4*)(smem + lcol * 72 + s * 8);
        *(uint4*)(Vt + (size_t)(c0 + lcol) * NTOK + grow0 + s * 8) = d;
      }
    } else {
      // row-major tile T[row 64][col 64 + pad8]
#pragma unroll
      for (int nt = 0; nt < 4; ++nt)
#pragma unroll
        for (int r = 0; r < 4; ++r)
          smem[(wave * 16 + q4 * 4 + r) * 72 + nt * 16 + l15] =
              f2bf(acc[nt][r] + bc[nt]);
      __syncthreads();
#pragma unroll
      for (int i = 0; i < 2; ++i) {
        int chn = i * 256 + tid;        // 512 chunks of 16B
        int lrow = chn >> 3, g = chn & 7;
        uint4 d = *(const uint4*)(smem + lrow * 72 + g * 8);
        int grow = grow0 + lrow, gc = c0 + g * 8;
        if (which == 1)
          *(uint4*)(Kb + (size_t)grow * 256 + gc) = d;
        else
          *(uint4*)(Qb + (size_t)((grow >> 5) * 16 + (gc >> 4)) * 512 +
                    ((gc >> 3) & 1) * 256 + (grow & 31) * 8) = d;
      }
    }
  }
#undef STAGEW
}

// ---------------------------------------------------------------------------
// Kernel 2: flash attention — main loop byte-identical to R7 (frozen).
//  NEW: fused split-K combine tail. Each block: threadfence + atomicAdd on
//  cnt[rb]; the 8th (last) block for a row-group combines its 256 rows
//  (standard split-K reduction pattern, device-scope fence per G16) and
//  writes the final f32 output with residual. Removes the combine launch
//  and its full-GPU drain; cnt re-zeroed by prep each replay; a stale cnt
//  in a rocprof single-kernel replay just skips the tail (no spin).
// ---------------------------------------------------------------------------
__global__ __launch_bounds__(512, 2) void attn_kernel(
    const u16* __restrict__ Qb, const u16* __restrict__ Kb,
    const u16* __restrict__ Vt, const u16* __restrict__ Qp,
    const u16* __restrict__ Kp, u16* __restrict__ Op,
    float* __restrict__ ml, const float* __restrict__ X,
    float* __restrict__ out, int* __restrict__ cnt) {
  __shared__ u16 kbuf[2][BN * 256];               // 32 KB x2  [key][256]
  __shared__ u16 vbuf[2][256 * BN];               // 32 KB x2  [feat][64]
  __shared__ u16 kpbuf[2][BN * 16];               // 2 KB x2   [key][16]
  __shared__ float sden[256];
  __shared__ int sh_flag;

  const int tid = threadIdx.x;
  const int lane = tid & 63;
  const int wave = tid >> 6;
  const int l31 = lane & 31;
  const int h5 = lane >> 5;
  const int sp = blockIdx.x;
  const int rb = blockIdx.y;
  const int q0 = rb * 256;
  const int wrow = wave * 32;

#define STAGE(T, S_)                                                          \
  do {                                                                        \
    const int key0_ = sp * SPLEN + (T) * BN;                                  \
    _Pragma("unroll")                                                         \
    for (int j = 0; j < 4; ++j) {                                             \
      int r = wave * 8 + j * 2 + (lane >> 5);                                 \
      int c = (lane & 31) ^ (r & 7);                                          \
      async16(Kb + (size_t)(key0_ + r) * 256 + c * 8,                         \
              &kbuf[S_][(wave * 8 + j * 2) * 256]);                           \
    }                                                                         \
    _Pragma("unroll")                                                         \
    for (int j = 0; j < 4; ++j) {                                             \
      int f = wave * 32 + j * 8 + (lane >> 3);                                \
      int c = (lane & 7) ^ (f & 7);                                           \
      async16(Vt + (size_t)f * NTOK + key0_ + c * 8,                          \
              &vbuf[S_][(wave * 32 + j * 8) * BN]);                           \
    }                                                                         \
    if (wave == 0) {                                                          \
      _Pragma("unroll")                                                       \
      for (int hh = 0; hh < 2; ++hh)                                          \
        async16(Kp + (size_t)(key0_ + hh * 32 + (lane >> 1)) * 16 +           \
                    (lane & 1) * 8,                                           \
                &kpbuf[S_][hh * 32 * 16]);                                    \
    }                                                                         \
  } while (0)

  // ---- Q fragments (loop-invariant, coalesced from frag-layout Qb) ----
  const int rb32 = rb * 8 + wave;
  bf16x8 qa[16];
#pragma unroll
  for (int kc = 0; kc < 16; ++kc)
    qa[kc] = *(const bf16x8*)(Qb + ((size_t)(rb32 * 16 + kc) * 64 + lane) * 8);

  // position B-fragment for this lane's qrow (col = lane&31 in S^T layout)
  const bf16x8 qp = *(const bf16x8*)(Qp + (size_t)(q0 + wrow + l31) * 16 +
                                     h5 * 8);

  f32x16 O[8];
#pragma unroll
  for (int ft = 0; ft < 8; ++ft)
#pragma unroll
    for (int r = 0; r < 16; ++r) O[ft][r] = 0.f;
  float lrow = 0.f;

  const int swz = l31 & 7;

  STAGE(0, 0);

#pragma unroll 1
  for (int t = 0; t < ITERS; ++t) {
    const int slot = t & 1;
    asm volatile("s_waitcnt vmcnt(0)" ::: "memory");
    __builtin_amdgcn_s_barrier();
    if (t + 1 < ITERS) STAGE(t + 1, slot ^ 1);

#pragma unroll
    for (int sub = 0; sub < 2; ++sub) {
      // ---- T = decay-exponent MFMA ----
      f32x16 T;
#pragma unroll
      for (int r = 0; r < 16; ++r) T[r] = 0.f;
      {
        bf16x8 kpf = *(const bf16x8*)(&kpbuf[slot][(sub * 32 + l31) * 16 +
                                      h5 * 8]);
        T = mfma32(kpf, qp, T);
      }

      // ---- S^T = K Q^T : D[key][qrow], 32 keys x 32 rows ----
      f32x16 S;
#pragma unroll
      for (int r = 0; r < 16; ++r) S[r] = 0.f;
      __builtin_amdgcn_s_setprio(1);
#pragma unroll
      for (int kc = 0; kc < 16; ++kc) {
        bf16x8 kf = *(const bf16x8*)(&kbuf[slot][(sub * 32 + l31) * 256 +
                                     (((2 * kc + h5) ^ swz) * 8)]);
        S = mfma32(kf, qa[kc], S);
      }
      __builtin_amdgcn_s_setprio(0);

      // ---- softmax: dec = exp2(-t*log2e + DECC); p = exp2(S*dec) ----
#pragma unroll
      for (int r = 0; r < 16; ++r) {
        float dec = exp2_hw(fmaf(T[r], -LOG2E, DECC));
        float p = exp2_hw(S[r] * dec);
        S[r] = p;
        lrow += p;
      }

      // ---- pack P to bf16 A-frags in-register ----
      uint32_t w0, w1, w2, w3, w4, w5, w6, w7;
      asm("v_cvt_pk_bf16_f32 %0, %1, %2" : "=v"(w0) : "v"(S[0]),  "v"(S[1]));
      asm("v_cvt_pk_bf16_f32 %0, %1, %2" : "=v"(w1) : "v"(S[2]),  "v"(S[3]));
      asm("v_cvt_pk_bf16_f32 %0, %1, %2" : "=v"(w2) : "v"(S[4]),  "v"(S[5]));
      asm("v_cvt_pk_bf16_f32 %0, %1, %2" : "=v"(w3) : "v"(S[6]),  "v"(S[7]));
      asm("v_cvt_pk_bf16_f32 %0, %1, %2" : "=v"(w4) : "v"(S[8]),  "v"(S[9]));
      asm("v_cvt_pk_bf16_f32 %0, %1, %2" : "=v"(w5) : "v"(S[10]), "v"(S[11]));
      asm("v_cvt_pk_bf16_f32 %0, %1, %2" : "=v"(w6) : "v"(S[12]), "v"(S[13]));
      asm("v_cvt_pk_bf16_f32 %0, %1, %2" : "=v"(w7) : "v"(S[14]), "v"(S[15]));
      asm volatile("v_permlane32_swap_b32 %0, %1" : "+v"(w2), "+v"(w0));
      asm volatile("v_permlane32_swap_b32 %0, %1" : "+v"(w3), "+v"(w1));
      asm volatile("v_permlane32_swap_b32 %0, %1" : "+v"(w6), "+v"(w4));
      asm volatile("v_permlane32_swap_b32 %0, %1" : "+v"(w7), "+v"(w5));
      PW pa0, pa1;
      pa0.u[0] = w0; pa0.u[1] = w1; pa0.u[2] = w2; pa0.u[3] = w3;
      pa1.u[0] = w4; pa1.u[1] = w5; pa1.u[2] = w6; pa1.u[3] = w7;

      // ---- O += P V (full 256 features, 8 ft-blocks of 32) ----
      __builtin_amdgcn_s_setprio(1);
#pragma unroll
      for (int kh = 0; kh < 2; ++kh) {
        const bf16x8 pa = kh ? pa1.v : pa0.v;
        const int khh = sub * 2 + kh;
#pragma unroll
        for (int ft = 0; ft < 8; ++ft) {
          bf16x8 vf = *(const bf16x8*)(&vbuf[slot][(ft * 32 + l31) * BN +
                                       (((2 * khh + h5) ^ swz) * 8)]);
          O[ft] = mfma32(pa, vf, O[ft]);
        }
      }
      __builtin_amdgcn_s_setprio(0);
    }
  }

  // ---- epilogue: write this split's partials ----
  float lsum = lrow + __shfl_xor(lrow, 32);
#pragma unroll
  for (int ft = 0; ft < 8; ++ft)
#pragma unroll
    for (int r = 0; r < 16; ++r) {
      int row = q0 + wrow + (r & 3) + 8 * (r >> 2) + 4 * h5;
      Op[((size_t)sp * NTOK + row) * 256 + ft * 32 + l31] = f2bf(O[ft][r]);
    }
  if (lane < 32)
    ml[sp * NTOK + q0 + wrow + lane] = lsum;

  // ---- fused split-K combine: last block per row-group reduces ----
  __threadfence();                       // publish Op/ml device-wide
  if (tid == 0) sh_flag = atomicAdd(&cnt[rb], 1);
  __syncthreads();
  if (sh_flag == KSPLIT - 1) {
    __threadfence();                     // acquire other splits' writes
    for (int r0 = tid; r0 < 256; r0 += 512) {
      float den = 1.f;
#pragma unroll
      for (int s = 0; s < KSPLIT; ++s) den += ml[s * NTOK + q0 + r0];
      sden[r0] = 1.f / den;
    }
    __syncthreads();
#pragma unroll 1
    for (int i = 0; i < 64; ++i) {
      int idx = i * 512 + tid;           // 256 rows x 128 float2 cols
      int lr = idx >> 7;
      int f2 = idx & 127;
      int row = q0 + lr;
      float n0 = 0.f, n1 = 0.f;
#pragma unroll
      for (int s = 0; s < KSPLIT; ++s) {
        uint32_t v = *(const uint32_t*)(Op + ((size_t)s * NTOK + row) * 256 +
                                        f2 * 2);
        n0 += bf2f((u16)v);
        n1 += bf2f((u16)(v >> 16));
      }
      const float inv = sden[lr];
      float2 o;
      o.x = n0 * inv + X[(size_t)row * XSTRIDE + f2 * 2];
      o.y = n1 * inv + X[(size_t)row * XSTRIDE + f2 * 2 + 1];
      *(float2*)(out + (size_t)row * 256 + f2 * 2) = o;
    }
  }
#undef STAGE
}

// ---------------------------------------------------------------------------
extern "C" void kernel_launch(void* const* d_in, const int* in_sizes, int n_in,
                              void* d_out, int out_size, void* d_ws, size_t ws_size,
                              hipStream_t stream) {
  (void)in_sizes; (void)n_in; (void)out_size; (void)ws_size;
  const float* X  = (const float*)d_in[0];
  const float* WQ = (const float*)d_in[1];
  const float* bQ = (const float*)d_in[2];
  const float* WK = (const float*)d_in[3];
  const float* bK = (const float*)d_in[4];
  const float* WV = (const float*)d_in[5];
  const float* bV = (const float*)d_in[6];
  float* out = (float*)d_out;
  char* ws = (char*)d_ws;

  // ws: Qb 4M | Kb 4M | Vt 4M | Qp 256K | Kp 256K | Wt 384K | (unused 4M) |
  //     ml 256K | cnt 128B | Op 32M   (offsets unchanged from R7)
  u16*   Qb = (u16*)(ws);
  u16*   Kb = (u16*)(ws + ((size_t)4 << 20));
  u16*   Vt = (u16*)(ws + ((size_t)8 << 20));
  u16*   Qp = (u16*)(ws + ((size_t)12 << 20));
  u16*   Kp = (u16*)(ws + ((size_t)12 << 20) + 262144);
  u16*   Wt = (u16*)(ws + ((size_t)12 << 20) + 524288);
  float* ml = (float*)(ws + ((size_t)16 << 20) + 524288 + 393216);
  int*   cnt = (int*)(ws + ((size_t)16 << 20) + 524288 + 393216 + 262144);
  u16*   Op = (u16*)(ws + ((size_t)16 << 20) + 524288 + 393216 + 524288);

  prep_kernel<<<dim3(56), dim3(256), 0, stream>>>(X, WQ, WK, WV,
                                                  Qp, Kp, Wt, cnt);
  qkv_kernel<<<dim3(128, 3), dim3(256), 0, stream>>>(X, Wt, bQ, bK, bV,
                                                     Qb, Kb, Vt);
  attn_kernel<<<dim3(KSPLIT, NTOK / 256), dim3(512), 0, stream>>>(
      Qb, Kb, Vt, Qp, Kp, Op, ml, X, out, cnt);
}